// Round 15
// baseline (125.000 us; speedup 1.0000x reference)
//
#include <hip/hip_runtime.h>
#include <hip/hip_bf16.h>
#include <math.h>

#ifndef M_PI
#define M_PI 3.14159265358979323846
#endif

#define T 2048
#define EDGE 256
#define TT 1536            // trimmed timesteps
#define PHA_N 50
#define AMP_N 30
#define NBANDS 80
#define NBINS 18
#define NBC 16             // B*C = 2*8
#define FMAX 768           // forward DFT bins stored [0, FMAX); max needed bin = 634
#define NCH 16             // t-chunks for forward DFT
#define CHLEN (T / NCH)    // 128
#define NW 12              // f-chunks / waves per band block
#define CS 53              // f-steps per chunk (12*53 = 636 >= 634)
#define TPB (NW * 64)      // 768 threads
#define NEV (2 * NBANDS)   // 160 snapshot events

typedef __attribute__((ext_vector_type(8))) short short8;       // 8x16-bit
typedef __attribute__((ext_vector_type(8))) _Float16 half8;     // 8 f16 (4 VGPRs)
typedef __attribute__((ext_vector_type(16))) float float16;     // 32x32 C/D frag

// Inclusive frequency-bin range [fl, fh] for a band, replicating the
// reference's float32 band edges vs exact quarter-Hz freq grid.
__device__ __forceinline__ void band_range(int band, int* fl, int* fh) {
    double lo, hi;
    if (band < PHA_N) {
        double mid = 2.0 + (double)band * (18.0 / 49.0);   // linspace(2,20,50)
        lo = (double)(float)(mid * 0.75);
        hi = (double)(float)(mid * 1.25);
    } else {
        int j = band - PHA_N;
        double mid = 60.0 + (double)j * (81.0 / 29.0);     // linspace(60,141,30)
        lo = (double)(float)(mid * 0.875);
        hi = (double)(float)(mid * 1.125);
    }
    int l = (int)ceil(lo * 4.0);     // freq = 0.25*f ; f >= 4*lo
    int h = (int)floor(hi * 4.0);    // f <= 4*hi
    if (l < 1) l = 1;
    if (h > FMAX - 1) h = FMAX - 1;
    *fl = l; *fh = h;
}

// Kernel A: chunked forward DFT partials (fp64). Two independent 64-step
// oscillator chains per thread; Xp layout ch-slowest for coalesced writes.
__global__ void dft_kernel(const float* __restrict__ x, double* __restrict__ Xp) {
    __shared__ float xs[CHLEN];
    const int bc = blockIdx.x;
    const int fb = blockIdx.y;
    const int ch = blockIdx.z;
    const int tid = threadIdx.x;
    const int t0 = ch * CHLEN;
    if (tid < CHLEN) xs[tid] = x[bc * T + t0 + tid];
    __syncthreads();
    const int f = fb * 256 + tid;
    const double om = 2.0 * M_PI / (double)T;
    double s, c;
    sincos(om * (double)(f & (T - 1)), &s, &c);
    const double wR = c, wI = -s;                       // e^{-i om f}
    double curR[2], curI[2], accR[2], accI[2];
    #pragma unroll
    for (int h = 0; h < 2; ++h) {
        sincos(om * (double)((f * (t0 + h * 64)) & (T - 1)), &s, &c);
        curR[h] = c; curI[h] = -s;                      // e^{-i om f (t0+64h)}
        accR[h] = 0.0; accI[h] = 0.0;
    }
    #pragma unroll 2
    for (int t = 0; t < 64; ++t) {
        #pragma unroll
        for (int h = 0; h < 2; ++h) {
            double v = (double)xs[t + h * 64];
            accR[h] += v * curR[h];
            accI[h] += v * curI[h];
            double nR = curR[h] * wR - curI[h] * wI;
            double nI = curR[h] * wI + curI[h] * wR;
            curR[h] = nR; curI[h] = nI;
        }
    }
    const size_t o = (size_t)((ch * NBC + bc) * FMAX + f) * 2;
    Xp[o + 0] = accR[0] + accR[1];
    Xp[o + 1] = accI[0] + accI[1];
}

// Kernel B (R14 restructure): band synthesis via PREFIX SUM over frequency.
// S_band = P[fh] - P[fl-1], P[f][t] = sum_{g<=f} X[g] e^{i om g t}.
// One block per (bc, 64-t group); wave w = f-chunk [1+53w .. 53(w+1)].
// Snapshots of the chunk-local prefix at the 160 band-boundary f's -> LDS;
// chunk totals -> carries -> assembly (atan2f -> idx, sqrtf -> f16 Abuf).
// Op count: 634 prefix steps/(bc,t) vs Sum(nb)=4155 per-band steps (6.5x cut).
// fp32 cancellation: err ~6e-8*sqrt(634/nb) <= 1e-6 rad vs 0.349 bin width.
__global__ __launch_bounds__(TPB)
void band_kernel(const double* __restrict__ Xp,
                 unsigned char* __restrict__ idx_buf,
                 _Float16* __restrict__ Abuf) {
    __shared__ float sXr[640], sXi[640];          // staged Xf, index 1..634
    __shared__ float snapR[NEV][64];              // prefix snapshots (80 KB)
    __shared__ float snapI[NEV][64];
    __shared__ float totR[NW][64], totI[NW][64];  // chunk totals
    __shared__ float carR[NW][64], carI[NW][64];  // carries (sum of prev chunks)
    __shared__ int bfl[NBANDS], bfh[NBANDS];
    __shared__ int ef[NEV];                       // event f per slot
    __shared__ short srt_f[NEV];                  // events sorted by f
    __shared__ unsigned char srt_s[NEV];          // slot of sorted event
    __shared__ int cstart[NW];                    // first sorted-event idx per chunk
    const int bc = blockIdx.x;
    const int tg = blockIdx.y;                    // t-group (64 t's)
    const int tid = threadIdx.x;
    const int wave = tid >> 6, lane = tid & 63;
    const int t = tg * 64 + lane + EDGE;          // absolute time index

    // stage Xf[1..634]: sum the 16 L2-resident Xp chunk partials (fp64 acc)
    for (int i = tid; i < 634; i += TPB) {
        const int f = i + 1;
        double r = 0.0, im = 0.0;
        #pragma unroll
        for (int c = 0; c < NCH; ++c) {
            const size_t o = (size_t)((c * NBC + bc) * FMAX + f) * 2;
            r += Xp[o]; im += Xp[o + 1];
        }
        sXr[f] = (float)r; sXi[f] = (float)im;
    }
    if (tid < NBANDS) { int fl, fh; band_range(tid, &fl, &fh); bfl[tid] = fl; bfh[tid] = fh; }
    if (tid < NW) cstart[tid] = NEV;
    __syncthreads();
    if (tid < NEV) ef[tid] = (tid & 1) ? bfh[tid >> 1] : bfl[tid >> 1] - 1;  // all >= 5
    __syncthreads();
    if (tid < NEV) {
        const int fe = ef[tid];
        int rank = 0;
        for (int j = 0; j < NEV; ++j) {          // broadcast reads, O(160)
            const int fj = ef[j];
            rank += (fj < fe || (fj == fe && j < tid)) ? 1 : 0;
        }
        srt_f[rank] = (short)fe;
        srt_s[rank] = (unsigned char)tid;
        atomicMin(&cstart[(fe - 1) / CS], rank); // native int LDS atomic [R8]
    }
    __syncthreads();

    // chunk-local prefix with snapshots at events (wave-uniform schedule)
    const int g0 = wave * CS + 1;
    const int g1 = min(g0 + CS - 1, 634);
    int ptr = cstart[wave];
    int nf = (ptr < NEV) ? (int)srt_f[ptr] : 10000;
    const float omf = (float)(2.0 * M_PI / (double)T);
    float ss, cc;
    sincosf(omf * (float)(t & (T - 1)), &ss, &cc);          // step e^{i om t}
    float Er, Ei;
    { float s0, c0; sincosf(omf * (float)(((g0 - 1) * t) & (T - 1)), &s0, &c0);
      Er = c0; Ei = s0; }                                   // e^{i om (g0-1) t}
    float Pr = 0.0f, Pi = 0.0f;
    for (int g = g0; g <= g1; ++g) {
        const float nEr = Er * cc - Ei * ss;
        const float nEi = Er * ss + Ei * cc;
        Er = nEr; Ei = nEi;
        const float Xr = sXr[g], Xi = sXi[g];               // broadcast read
        Pr += Xr * Er - Xi * Ei;
        Pi += Xr * Ei + Xi * Er;
        while (g == nf) {                                   // LDS touched on match only
            const int slot = srt_s[ptr];
            snapR[slot][lane] = Pr;
            snapI[slot][lane] = Pi;
            ++ptr;
            nf = (ptr < NEV) ? (int)srt_f[ptr] : 10000;
        }
    }
    totR[wave][lane] = Pr; totI[wave][lane] = Pi;
    __syncthreads();
    {
        float cr = 0.0f, ci = 0.0f;
        for (int w = 0; w < wave; ++w) { cr += totR[w][lane]; ci += totI[w][lane]; }
        carR[wave][lane] = cr; carI[wave][lane] = ci;
    }
    __syncthreads();

    // assembly: band sum = (snap_hi + carry_hi) - (snap_lo + carry_lo)
    const float widthf = (float)(2.0 * M_PI / (double)NBINS);
    const float pif = (float)M_PI;
    for (int o = tid; o < NBANDS * 64; o += TPB) {
        const int band = o >> 6, tl = o & 63;
        const int fl = bfl[band], fh = bfh[band];
        const int clo = (fl - 2) / CS;           // chunk of f = fl-1
        const int chi = (fh - 1) / CS;           // chunk of f = fh
        const float PloR = snapR[2 * band][tl] + carR[clo][tl];
        const float PloI = snapI[2 * band][tl] + carI[clo][tl];
        const float PhiR = snapR[2 * band + 1][tl] + carR[chi][tl];
        const float PhiI = snapI[2 * band + 1][tl] + carI[chi][tl];
        const float Sr = PhiR - PloR;
        const float Si = PhiI - PloI;
        const int trel = tg * 64 + tl;
        if (band < PHA_N) {
            float pha = atan2f(Si, Sr);                     // (-pi, pi]
            int b = (int)floorf((pha + pif) / widthf);
            if (b < 0) b = 0;
            if (b > NBINS - 1) b = NBINS - 1;
            idx_buf[(size_t)(bc * PHA_N + band) * TT + trel] = (unsigned char)b;
        } else {
            float amp = sqrtf(Sr * Sr + Si * Si) * (2.0f / (float)T);
            Abuf[(size_t)(bc * 32 + (band - PHA_N)) * TT + trel] = (_Float16)amp;
        }
    }
    if (tid < 64)   // ones (counts) row
        Abuf[(size_t)(bc * 32 + 30) * TT + tg * 64 + tid] = (_Float16)1.0f;
}

// Kernel C: bin-sum as f16 MFMA matmul + inline MI epilogue (frozen since R12).
// Per (bc,p) block: C[31x18] = A[31x1536](f16 amp+ones) x Onehot[1536x18].
__global__ void mi_kernel(const unsigned char* __restrict__ idx_buf,
                          const _Float16* __restrict__ Abuf,
                          float* __restrict__ out) {
    __shared__ unsigned int sidx_s[TT / 4];       // 384 packed idx words
    __shared__ float cpart[4][32][NBINS];         // per-kquarter C partials
    const int blk = blockIdx.x;                   // bc*50 + p
    const int bc = blk / PHA_N;
    const int p = blk % PHA_N;
    const int tid = threadIdx.x;
    const int wave = tid >> 6;                    // k-quarter 0..3
    const int lane = tid & 63;

    for (int i = tid; i < TT / 4; i += 256)
        sidx_s[i] = ((const unsigned int*)(idx_buf + (size_t)(bc * PHA_N + p) * TT))[i];
    __syncthreads();

    const int n = lane & 31;                      // A row m == B col n == lane&31
    const int kq = lane >> 5;                     // k-quad: 0 or 1 (8 k's each)
    const half8* arow = (const half8*)(Abuf + (size_t)(bc * 32 + n) * TT
                                       + wave * 384 + kq * 8);
    float16 acc = {0.0f};
    #pragma unroll 4
    for (int ks = 0; ks < 24; ++ks) {
        const half8 a = arow[ks * 2];             // K-step stride = 16 f16 = 2 half8
        const int w0 = wave * 96 + ks * 4 + kq * 2;
        const unsigned int lo = sidx_s[w0];
        const unsigned int hi = sidx_s[w0 + 1];
        short8 bs;
        bs[0] = ((lo & 0xffu) == (unsigned)n) ? (short)0x3C00 : (short)0;   // f16 1.0
        bs[1] = (((lo >> 8) & 0xffu) == (unsigned)n) ? (short)0x3C00 : (short)0;
        bs[2] = (((lo >> 16) & 0xffu) == (unsigned)n) ? (short)0x3C00 : (short)0;
        bs[3] = ((lo >> 24) == (unsigned)n) ? (short)0x3C00 : (short)0;
        bs[4] = ((hi & 0xffu) == (unsigned)n) ? (short)0x3C00 : (short)0;
        bs[5] = (((hi >> 8) & 0xffu) == (unsigned)n) ? (short)0x3C00 : (short)0;
        bs[6] = (((hi >> 16) & 0xffu) == (unsigned)n) ? (short)0x3C00 : (short)0;
        bs[7] = ((hi >> 24) == (unsigned)n) ? (short)0x3C00 : (short)0;
        const half8 b = __builtin_bit_cast(half8, bs);
        acc = __builtin_amdgcn_mfma_f32_32x32x16_f16(a, b, acc, 0, 0, 0);
    }

    // scatter C frag to LDS (cols >= NBINS and row 31 discarded)
    if (n < NBINS) {
        #pragma unroll
        for (int r = 0; r < 16; ++r) {
            const int row = (r & 3) + 8 * (r >> 2) + 4 * kq;
            if (row < 31) cpart[wave][row][n] = acc[r];
        }
    }
    __syncthreads();

    // MI epilogue: thread a < 30 computes out[blk*30 + a]
    if (tid < AMP_N) {
        const int a = tid;
        double m[NBINS], tot = 0.0;
        #pragma unroll
        for (int k = 0; k < NBINS; ++k) {
            double cnt = (double)(cpart[0][30][k] + cpart[1][30][k]
                                + cpart[2][30][k] + cpart[3][30][k]);     // counts
            double denom = cnt > 1e-9 ? cnt : 1e-9;
            double s = (double)(cpart[0][a][k] + cpart[1][a][k]
                              + cpart[2][a][k] + cpart[3][a][k]);
            m[k] = s / denom;
            tot += m[k];
        }
        double dt = tot > 1e-9 ? tot : 1e-9;
        double accm = 0.0;
        #pragma unroll
        for (int k = 0; k < NBINS; ++k) {
            double pr = m[k] / dt;
            accm += pr * log(pr + 1e-9);
        }
        const double lognb = log((double)NBINS);
        out[(size_t)blk * AMP_N + a] = (float)((lognb + accm) / lognb);
    }
}

extern "C" void kernel_launch(void* const* d_in, const int* in_sizes, int n_in,
                              void* d_out, int out_size, void* d_ws, size_t ws_size,
                              hipStream_t stream) {
    const float* x = (const float*)d_in[0];
    float* out = (float*)d_out;
    char* ws = (char*)d_ws;
    // workspace layout (~5.9 MB; all regions written before read each call):
    //   idx_buf: 16*50*1536 u8                       = 1,228,800 B @ 0
    //   Abuf:    16*32*1536 f16                      = 1,572,864 B @ 1,228,800
    //   Xp:      16 chunks * 16*768 complex double   = 3,145,728 B @ 2,801,664
    unsigned char* idx_buf = (unsigned char*)ws;
    _Float16* Abuf = (_Float16*)(ws + 1228800);
    double* Xp = (double*)(ws + 2801664);

    dft_kernel<<<dim3(NBC, FMAX / 256, NCH), 256, 0, stream>>>(x, Xp);
    band_kernel<<<dim3(NBC, TT / 64), TPB, 0, stream>>>(Xp, idx_buf, Abuf);
    mi_kernel<<<NBC * PHA_N, 256, 0, stream>>>(idx_buf, Abuf, out);
}